// Round 13
// baseline (171.480 us; speedup 1.0000x reference)
//
#include <hip/hip_runtime.h>
#include <math.h>
#include <float.h>

#define BN 32
#define CH 3
#define HH 512
#define WW 512
#define NP 4
#define EPS 128
#define HALF 64
#define MARGIN 32

#define NT 4096                                  // 64x64 grid of 8x8 tiles per map
#define PATCH_ELEMS (BN * NP * CH * EPS * EPS)   // 6291456
#define F4_PER_MAP (NP * CH * EPS * EPS / 4)     // 49152 (12 planes * 4096 f4)
#define F4_PER_PATCH (F4_PER_MAP / NP)           // 12288
#define NSLICE 16
#define K1_NTHR 256
#define K1_NBLK (BN * NT / K1_NTHR)              // 512

typedef float f4v __attribute__((ext_vector_type(4), aligned(4)));  // elem-aligned vec

// NOTE (R5/R7/R11 lessons, thrice-measured): EVERY intra-kernel cross-block
// coordination scheme on MI355X (spin-wait, cg::grid.sync, fence+atomic
// last-block takeover) loses >20us vs a plain stream-ordered kernel boundary.
// Dataflow crosses kernels; period.
// R13: class->slice rebalance {6,4,3,3} so late-starting chain classes move
// more data per block but finish together with early chain-free classes.

// ============ K1: per-tile (max,argmax) for all maps, computed ONCE =========
__global__ __launch_bounds__(K1_NTHR)
void tile_scan(const float* __restrict__ umaps, float2* __restrict__ tiles,
               float2* __restrict__ l2g)
{
    const int g  = blockIdx.x * K1_NTHR + threadIdx.x;
    const int b  = g >> 12;                      // map
    const int t  = g & (NT - 1);                 // tile within map
    const int tx = t & 63, ty = t >> 6;          // lane == tx
    const float* __restrict__ um = umaps + (size_t)b * HH * WW;
    const int x0 = tx << 3, y0 = ty << 3;
    float bv = -INFINITY; int bi = 0x7fffffff;
    #pragma unroll
    for (int r = 0; r < 8; ++r) {
        const int rowbase = (y0 + r) * WW + x0;
        const float4 a = *(const float4*)(um + rowbase);
        const float4 c = *(const float4*)(um + rowbase + 4);
        if (a.x > bv) { bv = a.x; bi = rowbase + 0; }
        if (a.y > bv) { bv = a.y; bi = rowbase + 1; }
        if (a.z > bv) { bv = a.z; bi = rowbase + 2; }
        if (a.w > bv) { bv = a.w; bi = rowbase + 3; }
        if (c.x > bv) { bv = c.x; bi = rowbase + 4; }
        if (c.y > bv) { bv = c.y; bi = rowbase + 5; }
        if (c.z > bv) { bv = c.z; bi = rowbase + 6; }
        if (c.w > bv) { bv = c.w; bi = rowbase + 7; }
    }
    tiles[g] = make_float2(bv, __int_as_float(bi));
    float rv = bv; int ri = bi;
    #pragma unroll
    for (int off = 32; off > 0; off >>= 1) {
        const float ov = __shfl_down(rv, off);
        const int   oi = __shfl_down(ri, off);
        if (ov > rv || (ov == rv && oi < ri)) { rv = ov; ri = oi; }
    }
    const int lane = threadIdx.x & 63;
    if (lane == 0) l2g[b * 64 + ty] = make_float2(rv, __int_as_float(ri));
}

// ============ K2: redundant lazy selection + rebalanced slice extraction ====
// 512 blocks: b = blk&31, slice = blk>>5.
// slice->class: {0..5}->p0 (2 iters), {6..9}->p1 (3), {10..12}->p2 (4),
// {13..15}->p3 (4). Class 0 = chain-free fast path. slice 15 writes coords.
__global__ __launch_bounds__(1024)
void select_extract(const float* __restrict__ images,
                    const float* __restrict__ umaps,
                    const float2* __restrict__ tiles,
                    const float2* __restrict__ l2g,
                    float* __restrict__ out)
{
    const int tid   = threadIdx.x;
    const int lane  = tid & 63;
    const int wave  = tid >> 6;
    const int b     = blockIdx.x & (BN - 1);
    const int slice = blockIdx.x >> 5;
    // rebalanced class mapping
    const int nwant = (slice < 6) ? 0 : (slice < 10) ? 1 : (slice < 13) ? 2 : 3;
    const int jidx  = slice - ((nwant == 0) ? 0 : (nwant == 1) ? 6 :
                               (nwant == 2) ? 10 : 13);
    const int sz    = (nwant == 0) ? 2048 : (nwant == 1) ? 3072 : 4096;
    const int fbase = nwant * F4_PER_PATCH + jidx * sz;
    const float* __restrict__ um = umaps + (size_t)b * HH * WW;
    const float2* __restrict__ tg = tiles + (size_t)b * NT;
    float* coords_out = out + PATCH_ELEMS;

    __shared__ float2   tvi[NT];      // valid only where rowvalid[row] set
    __shared__ float2   l2[64];
    __shared__ unsigned dirty[128];
    __shared__ int      rowvalid[64];
    __shared__ int      boxes[NP][4];
    __shared__ int      spx1, spy1;

    if (nwant == 0) {
        // ---- fast path: single-wave argmax straight from l2g (512B) --------
        if (wave == 0) {
            const float2 e = l2g[b * 64 + lane];
            float v = e.x; int ix = __float_as_int(e.y);
            #pragma unroll
            for (int off = 32; off > 0; off >>= 1) {
                const float ov = __shfl_down(v, off);
                const int   oi = __shfl_down(ix, off);
                if (ov > v || (ov == v && oi < ix)) { v = ov; ix = oi; }
            }
            ix = __shfl(ix, 0);
            if (lane == 0) {
                const int yc = ix >> 9, xc = ix & 511;
                int x1 = max(0, xc - HALF), x2 = min(WW, xc + HALF);
                int y1 = max(0, yc - HALF), y2 = min(HH, yc + HALF);
                if (x2 - x1 < EPS) { if (x1 == 0) x2 = EPS; else x1 = x2 - EPS; }
                if (y2 - y1 < EPS) { if (y1 == 0) y2 = EPS; else y1 = y2 - EPS; }
                spx1 = x1; spy1 = y1;
            }
        }
        __syncthreads();
    } else {
        // ---- slow path: lazy row-init tvi + lazy-dirty chain to nwant ------
        if (tid < 64)  { l2[tid] = l2g[b * 64 + tid]; rowvalid[tid] = 0; }
        if (tid < 128) dirty[tid] = 0u;
        if (tid < NP)  { boxes[tid][0] = 0; boxes[tid][1] = 0; boxes[tid][2] = 0; boxes[tid][3] = 0; }
        __syncthreads();

        for (int k = 0; k <= nwant; ++k) {
            if (wave == 0) {
                for (;;) {
                    const float2 e = l2[lane];
                    float v = e.x; int ix = __float_as_int(e.y);
                    #pragma unroll
                    for (int off = 32; off > 0; off >>= 1) {
                        const float ov = __shfl_down(v, off);
                        const int   oi = __shfl_down(ix, off);
                        if (ov > v || (ov == v && oi < ix)) { v = ov; ix = oi; }
                    }
                    ix = __shfl(ix, 0);
                    const int tt = ((ix >> 12) << 6) | ((ix & 511) >> 3);
                    const bool isdirty = (dirty[tt >> 5] >> (tt & 31)) & 1u;
                    if (!isdirty) {
                        if (lane == 0) {
                            const int yc = ix >> 9, xc = ix & 511;
                            int x1 = max(0, xc - HALF), x2 = min(WW, xc + HALF);
                            int y1 = max(0, yc - HALF), y2 = min(HH, yc + HALF);
                            if (x2 - x1 < EPS) { if (x1 == 0) x2 = EPS; else x1 = x2 - EPS; }
                            if (y2 - y1 < EPS) { if (y1 == 0) y2 = EPS; else y1 = y2 - EPS; }
                            boxes[k][0] = max(x1 - MARGIN, 0);
                            boxes[k][1] = min(x2 + MARGIN, WW);
                            boxes[k][2] = max(y1 - MARGIN, 0);
                            boxes[k][3] = min(y2 + MARGIN, HH);
                            if (k == nwant) { spx1 = x1; spy1 = y1; }
                            if (slice == NSLICE - 1) {        // one coord writer per map
                                const int o = (b * NP + k) * 4;
                                coords_out[o + 0] = (float)x1;
                                coords_out[o + 1] = (float)y1;
                                coords_out[o + 2] = (float)x2;
                                coords_out[o + 3] = (float)y2;
                            }
                        }
                        break;
                    }
                    // recompute dirty tile tt: 1 px per lane (row tyd is
                    // guaranteed rowvalid: dirty => processed by a repair pass)
                    const int tyd = tt >> 6, txd = tt & 63;
                    const int y = (tyd << 3) + (lane >> 3), x = (txd << 3) + (lane & 7);
                    float pv = um[y * WW + x];
                    int   pi = y * WW + x;
                    bool m = false;
                    #pragma unroll
                    for (int j = 0; j < NP; ++j)
                        m |= (y >= boxes[j][2] && y < boxes[j][3] &&
                              x >= boxes[j][0] && x < boxes[j][1]);
                    if (m) { pv = -INFINITY; pi = 0x7fffffff; }
                    float nv = pv; int ni = pi;
                    #pragma unroll
                    for (int off = 32; off > 0; off >>= 1) {
                        const float ov = __shfl_down(nv, off);
                        const int   oi = __shfl_down(ni, off);
                        if (ov > nv || (ov == nv && oi < ni)) { nv = ov; ni = oi; }
                    }
                    nv = __shfl(nv, 0); ni = __shfl(ni, 0);
                    if (lane == 0) {
                        tvi[tt] = make_float2(nv, __int_as_float(ni));
                        dirty[tt >> 5] &= ~(1u << (tt & 31));
                    }
                    // repair level2 row tyd (substitute new value in-register)
                    const float2 e2 = tvi[(tyd << 6) + lane];
                    float rv2; int ri2;
                    if (lane == txd) { rv2 = nv; ri2 = ni; }
                    else             { rv2 = e2.x; ri2 = __float_as_int(e2.y); }
                    #pragma unroll
                    for (int off = 32; off > 0; off >>= 1) {
                        const float ov = __shfl_down(rv2, off);
                        const int   oi = __shfl_down(ri2, off);
                        if (ov > rv2 || (ov == rv2 && oi < ri2)) { rv2 = ov; ri2 = oi; }
                    }
                    if (lane == 0) l2[tyd] = make_float2(rv2, __int_as_float(ri2));
                }
            }
            __syncthreads();

            if (k == nwant) break;

            // ---- merged repair pass for new box k: one wave per row --------
            const int ex1 = boxes[k][0], ex2 = boxes[k][1];
            const int ey1 = boxes[k][2], ey2 = boxes[k][3];
            const int ty1 = ey1 >> 3, ty2 = (ey2 - 1) >> 3;
            for (int r = ty1 + wave; r <= ty2; r += 16) {
                const int base = r << 6;
                float2 e;
                if (rowvalid[r]) e = tvi[base + lane];
                else             e = tg[base + lane];         // L2-hot global read
                float v = e.x; int ix = __float_as_int(e.y);
                const int X1 = lane << 3, Y1 = r << 3;
                const bool cov = (X1 >= ex1 && X1 + 8 <= ex2 &&
                                  Y1 >= ey1 && Y1 + 8 <= ey2);
                const bool ovl = (X1 < ex2 && X1 + 8 > ex1 &&
                                  Y1 < ey2 && Y1 + 8 > ey1);
                if (cov) { v = -INFINITY; ix = 0x7fffffff; }
                const unsigned long long dm = __ballot(ovl && !cov);
                tvi[base + lane] = make_float2(v, __int_as_float(ix));
                if (lane == 0) {
                    dirty[2 * r]     |= (unsigned)dm;
                    dirty[2 * r + 1] |= (unsigned)(dm >> 32);
                    rowvalid[r] = 1;
                }
                float rv = v; int ri = ix;
                #pragma unroll
                for (int off = 32; off > 0; off >>= 1) {
                    const float ov = __shfl_down(rv, off);
                    const int   oi = __shfl_down(ri, off);
                    if (ov > rv || (ov == rv && oi < ri)) { rv = ov; ri = oi; }
                }
                if (lane == 0) l2[r] = make_float2(rv, __int_as_float(ri));
            }
            __syncthreads();
        }
    }

    // ---- extraction: own class's share of patch nwant ----------------------
    const int x1 = spx1, y1 = spy1;
    f4v* __restrict__ out4 = (f4v*)out;
    #pragma unroll
    for (int it = 0; it < 4; ++it) {
        const int o = (it << 10) + tid;
        if (o < sz) {                         // uniform per block (sz mult of 1024)
            const int il  = fbase + o;        // within-map f4 idx
            const int nc  = il >> 12;         // plane; nc/3 == nwant by construction
            const int c   = nc - nwant * 3;
            const int py  = (il >> 5) & 127;
            const int px0 = (il & 31) << 2;

            const float* __restrict__ src =
                images + (((size_t)b * CH + c) * HH + (y1 + py)) * WW + x1 + px0;
            const f4v v = *(const f4v*)src;                   // elem-aligned dwordx4
            __builtin_nontemporal_store(v, &out4[(size_t)b * F4_PER_MAP + il]);
        }
    }
}

extern "C" void kernel_launch(void* const* d_in, const int* in_sizes, int n_in,
                              void* d_out, int out_size, void* d_ws, size_t ws_size,
                              hipStream_t stream) {
    const float* images = (const float*)d_in[0];
    const float* umaps  = (const float*)d_in[1];
    float* out          = (float*)d_out;
    float2* tiles       = (float2*)d_ws;                                // 1 MB
    float2* l2g         = tiles + (size_t)BN * NT;                      // 16 KB

    tile_scan<<<K1_NBLK, K1_NTHR, 0, stream>>>(umaps, tiles, l2g);
    select_extract<<<BN * NSLICE, 1024, 0, stream>>>(images, umaps, tiles, l2g, out);
}

// Round 14
// 168.652 us; speedup vs baseline: 1.0168x; 1.0168x over previous
//
#include <hip/hip_runtime.h>
#include <math.h>
#include <float.h>

#define BN 32
#define CH 3
#define HH 512
#define WW 512
#define NP 4
#define EPS 128
#define HALF 64
#define MARGIN 32

#define NT 4096                                  // 64x64 grid of 8x8 tiles per map
#define PATCH_ELEMS (BN * NP * CH * EPS * EPS)   // 6291456
#define F4_PER_MAP (NP * CH * EPS * EPS / 4)     // 49152 (12 planes * 4096 f4)
#define NSLICE 16
#define F4_PER_SLICE (F4_PER_MAP / NSLICE)       // 3072
#define K1_NTHR 256
#define K1_NBLK (BN * NT / K1_NTHR)              // 512

typedef float nf4 __attribute__((ext_vector_type(4)));   // native vec for nt-store

// NOTE (R5/R7/R11 lessons, thrice-measured): EVERY intra-kernel cross-block
// coordination scheme on MI355X (spin-wait, cg::grid.sync, fence+atomic
// last-block takeover) loses >20us vs a plain stream-ordered kernel boundary.
// R8 structure = measured champion (168.9us); R12/R13 variants tied within
// noise -> this is the structural floor given ~131us fixed harness overhead.

// ============ K1: per-tile (max,argmax) for all maps, computed ONCE =========
// Each wave covers one full tile row (lane == tx) => free per-row reduction
// into l2g (the level-2 argmax table select blocks would otherwise rebuild).
__global__ __launch_bounds__(K1_NTHR)
void tile_scan(const float* __restrict__ umaps, float2* __restrict__ tiles,
               float2* __restrict__ l2g)
{
    const int g  = blockIdx.x * K1_NTHR + threadIdx.x;
    const int b  = g >> 12;                      // map
    const int t  = g & (NT - 1);                 // tile within map
    const int tx = t & 63, ty = t >> 6;          // wave-uniform ty, tx == lane
    const float* __restrict__ um = umaps + (size_t)b * HH * WW;
    const int x0 = tx << 3, y0 = ty << 3;
    float bv = -INFINITY; int bi = 0x7fffffff;
    #pragma unroll
    for (int r = 0; r < 8; ++r) {
        const int rowbase = (y0 + r) * WW + x0;
        const float4 a = *(const float4*)(um + rowbase);
        const float4 c = *(const float4*)(um + rowbase + 4);
        if (a.x > bv) { bv = a.x; bi = rowbase + 0; }
        if (a.y > bv) { bv = a.y; bi = rowbase + 1; }
        if (a.z > bv) { bv = a.z; bi = rowbase + 2; }
        if (a.w > bv) { bv = a.w; bi = rowbase + 3; }
        if (c.x > bv) { bv = c.x; bi = rowbase + 4; }
        if (c.y > bv) { bv = c.y; bi = rowbase + 5; }
        if (c.z > bv) { bv = c.z; bi = rowbase + 6; }
        if (c.w > bv) { bv = c.w; bi = rowbase + 7; }
    }
    tiles[g] = make_float2(bv, __int_as_float(bi));
    // free per-row reduction (wave holds the whole tile row)
    float rv = bv; int ri = bi;
    #pragma unroll
    for (int off = 32; off > 0; off >>= 1) {
        const float ov = __shfl_down(rv, off);
        const int   oi = __shfl_down(ri, off);
        if (ov > rv || (ov == rv && oi < ri)) { rv = ov; ri = oi; }
    }
    const int lane = threadIdx.x & 63;
    if (lane == 0) l2g[b * 64 + ty] = make_float2(rv, __int_as_float(ri));
}

// ============ K2: fused redundant lazy selection + slice extraction =========
// 512 blocks: b = blk&31 (XCD spread), slice = blk>>5, nwant = slice>>2.
// Patch-0 blocks: one 512B l2g read + single-wave argmax, then extract.
// Others: 32KB tile cache + l2 seeded from l2g + lazy-dirty chain to nwant.
// Deterministic => all blocks of a map agree. slice 15 writes coords.
__global__ __launch_bounds__(1024)
void select_extract(const float* __restrict__ images,
                    const float* __restrict__ umaps,
                    const float2* __restrict__ tiles,
                    const float2* __restrict__ l2g,
                    float* __restrict__ out)
{
    const int tid   = threadIdx.x;
    const int lane  = tid & 63;
    const int wave  = tid >> 6;
    const int b     = blockIdx.x & (BN - 1);
    const int slice = blockIdx.x >> 5;
    const int nwant = slice >> 2;                 // the one patch this block extracts
    const float* __restrict__ um = umaps + (size_t)b * HH * WW;
    float* coords_out = out + PATCH_ELEMS;

    __shared__ float2   tvi[NT];
    __shared__ float2   l2[64];
    __shared__ unsigned dirty[128];
    __shared__ int      boxes[NP][4];
    __shared__ int      spx1, spy1;

    if (nwant == 0) {
        // ---- fast path: single-wave argmax straight from l2g (512B) --------
        if (wave == 0) {
            const float2 e = l2g[b * 64 + lane];
            float v = e.x; int ix = __float_as_int(e.y);
            #pragma unroll
            for (int off = 32; off > 0; off >>= 1) {
                const float ov = __shfl_down(v, off);
                const int   oi = __shfl_down(ix, off);
                if (ov > v || (ov == v && oi < ix)) { v = ov; ix = oi; }
            }
            ix = __shfl(ix, 0);
            if (lane == 0) {
                const int yc = ix >> 9, xc = ix & 511;
                int x1 = max(0, xc - HALF), x2 = min(WW, xc + HALF);
                int y1 = max(0, yc - HALF), y2 = min(HH, yc + HALF);
                if (x2 - x1 < EPS) { if (x1 == 0) x2 = EPS; else x1 = x2 - EPS; }
                if (y2 - y1 < EPS) { if (y1 == 0) y2 = EPS; else y1 = y2 - EPS; }
                spx1 = x1; spy1 = y1;
            }
        }
        __syncthreads();
    } else {
        // ---- slow path: tile cache + lazy-dirty greedy chain to nwant ------
        {
            const float4* __restrict__ src = (const float4*)(tiles + (size_t)b * NT);
            float4* dst = (float4*)tvi;
            dst[tid]        = src[tid];
            dst[tid + 1024] = src[tid + 1024];
        }
        if (tid < 64)  l2[tid] = l2g[b * 64 + tid];       // precomputed level2
        if (tid < 128) dirty[tid] = 0u;
        if (tid < NP)  { boxes[tid][0] = 0; boxes[tid][1] = 0; boxes[tid][2] = 0; boxes[tid][3] = 0; }
        __syncthreads();

        for (int k = 0; k <= nwant; ++k) {
            if (wave == 0) {
                for (;;) {
                    const float2 e = l2[lane];
                    float v = e.x; int ix = __float_as_int(e.y);
                    #pragma unroll
                    for (int off = 32; off > 0; off >>= 1) {
                        const float ov = __shfl_down(v, off);
                        const int   oi = __shfl_down(ix, off);
                        if (ov > v || (ov == v && oi < ix)) { v = ov; ix = oi; }
                    }
                    ix = __shfl(ix, 0);
                    const int t = ((ix >> 12) << 6) | ((ix & 511) >> 3);
                    const bool isdirty = (dirty[t >> 5] >> (t & 31)) & 1u;
                    if (!isdirty) {
                        if (lane == 0) {
                            const int yc = ix >> 9, xc = ix & 511;
                            int x1 = max(0, xc - HALF), x2 = min(WW, xc + HALF);
                            int y1 = max(0, yc - HALF), y2 = min(HH, yc + HALF);
                            if (x2 - x1 < EPS) { if (x1 == 0) x2 = EPS; else x1 = x2 - EPS; }
                            if (y2 - y1 < EPS) { if (y1 == 0) y2 = EPS; else y1 = y2 - EPS; }
                            boxes[k][0] = max(x1 - MARGIN, 0);
                            boxes[k][1] = min(x2 + MARGIN, WW);
                            boxes[k][2] = max(y1 - MARGIN, 0);
                            boxes[k][3] = min(y2 + MARGIN, HH);
                            if (k == nwant) { spx1 = x1; spy1 = y1; }
                            if (slice == NSLICE - 1) {        // one coord writer per map
                                const int o = (b * NP + k) * 4;
                                coords_out[o + 0] = (float)x1;
                                coords_out[o + 1] = (float)y1;
                                coords_out[o + 2] = (float)x2;
                                coords_out[o + 3] = (float)y2;
                            }
                        }
                        break;
                    }
                    // recompute dirty tile t: 1 px per lane
                    const int ty = t >> 6, tx = t & 63;
                    const int y = (ty << 3) + (lane >> 3), x = (tx << 3) + (lane & 7);
                    float pv = um[y * WW + x];
                    int   pi = y * WW + x;
                    bool m = false;
                    #pragma unroll
                    for (int j = 0; j < NP; ++j)
                        m |= (y >= boxes[j][2] && y < boxes[j][3] &&
                              x >= boxes[j][0] && x < boxes[j][1]);
                    if (m) { pv = -INFINITY; pi = 0x7fffffff; }
                    float nv = pv; int ni = pi;
                    #pragma unroll
                    for (int off = 32; off > 0; off >>= 1) {
                        const float ov = __shfl_down(nv, off);
                        const int   oi = __shfl_down(ni, off);
                        if (ov > nv || (ov == nv && oi < ni)) { nv = ov; ni = oi; }
                    }
                    nv = __shfl(nv, 0); ni = __shfl(ni, 0);
                    if (lane == 0) {
                        tvi[t] = make_float2(nv, __int_as_float(ni));
                        dirty[t >> 5] &= ~(1u << (t & 31));
                    }
                    // repair level2 row ty (substitute new value in-register)
                    const float2 e2 = tvi[(ty << 6) + lane];
                    float rv2; int ri2;
                    if (lane == tx) { rv2 = nv; ri2 = ni; }
                    else            { rv2 = e2.x; ri2 = __float_as_int(e2.y); }
                    #pragma unroll
                    for (int off = 32; off > 0; off >>= 1) {
                        const float ov = __shfl_down(rv2, off);
                        const int   oi = __shfl_down(ri2, off);
                        if (ov > rv2 || (ov == rv2 && oi < ri2)) { rv2 = ov; ri2 = oi; }
                    }
                    if (lane == 0) l2[ty] = make_float2(rv2, __int_as_float(ri2));
                }
            }
            __syncthreads();

            if (k == nwant) break;

            // eager cheap invalidation for new box k
            const int ex1 = boxes[k][0], ex2 = boxes[k][1];
            const int ey1 = boxes[k][2], ey2 = boxes[k][3];
            const int tx1 = ex1 >> 3, tx2 = (ex2 - 1) >> 3;
            const int ty1 = ey1 >> 3, ty2 = (ey2 - 1) >> 3;
            const int wt  = tx2 - tx1 + 1;
            const int nt2 = wt * (ty2 - ty1 + 1);      // <= 625
            if (tid < nt2) {
                const int tx = tx1 + tid % wt;
                const int ty = ty1 + tid / wt;
                const int t  = (ty << 6) + tx;
                const int X1 = tx << 3, Y1 = ty << 3;
                if (X1 >= ex1 && X1 + 8 <= ex2 && Y1 >= ey1 && Y1 + 8 <= ey2)
                    tvi[t] = make_float2(-INFINITY, __int_as_float(0x7fffffff));
                else
                    atomicOr(&dirty[t >> 5], 1u << (t & 31));
            }
            __syncthreads();

            // repair level2 for affected rows
            for (int r = ty1 + wave; r <= ty2; r += 16) {
                const float2 e = tvi[(r << 6) + lane];
                float v = e.x; int ix = __float_as_int(e.y);
                #pragma unroll
                for (int off = 32; off > 0; off >>= 1) {
                    const float ov = __shfl_down(v, off);
                    const int   oi = __shfl_down(ix, off);
                    if (ov > v || (ov == v && oi < ix)) { v = ov; ix = oi; }
                }
                if (lane == 0) l2[r] = make_float2(v, __int_as_float(ix));
            }
            __syncthreads();
        }
    }

    // ---- extraction: own map's 1/16 slice (single patch n = nwant) ---------
    const int x1 = spx1, y1 = spy1;
    nf4* __restrict__ out4 = (nf4*)out;
    #pragma unroll
    for (int it = 0; it < 3; ++it) {
        const int il  = slice * F4_PER_SLICE + (it << 10) + tid;  // within-map f4 idx
        const int nc  = il >> 12;            // plane; n == nwant by construction
        const int c   = nc - nwant * 3;
        const int py  = (il >> 5) & 127;
        const int px0 = (il & 31) << 2;

        const float* __restrict__ src =
            images + (((size_t)b * CH + c) * HH + (y1 + py)) * WW + x1 + px0;
        const nf4 v = { src[0], src[1], src[2], src[3] };
        __builtin_nontemporal_store(v, &out4[(size_t)b * F4_PER_MAP + il]);
    }
}

extern "C" void kernel_launch(void* const* d_in, const int* in_sizes, int n_in,
                              void* d_out, int out_size, void* d_ws, size_t ws_size,
                              hipStream_t stream) {
    const float* images = (const float*)d_in[0];
    const float* umaps  = (const float*)d_in[1];
    float* out          = (float*)d_out;
    float2* tiles       = (float2*)d_ws;                                // 1 MB
    float2* l2g         = tiles + (size_t)BN * NT;                      // 16 KB

    tile_scan<<<K1_NBLK, K1_NTHR, 0, stream>>>(umaps, tiles, l2g);
    select_extract<<<BN * NSLICE, 1024, 0, stream>>>(images, umaps, tiles, l2g, out);
}